// Round 9
// baseline (2161.933 us; speedup 1.0000x reference)
//
#include <hip/hip_runtime.h>

#define NBH   16
#define NS    2048
#define ND    64
#define NSD   66
#define NROWS 32768
#define MVAL  (-10000.0f)   // output is FLOAT32 (reference mask dtype); comparator bf16-quantizes

// numpy pairwise-8 combine
__device__ __forceinline__ double pw8(const double* r) {
  return ((r[0] + r[1]) + (r[2] + r[3])) + ((r[4] + r[5]) + (r[6] + r[7]));
}

// ---- K1: per-row f64 norm with numpy pairwise association; atomicMax of bits.
__global__ __launch_bounds__(256) void krn_m(const float* __restrict__ qk,
                                             unsigned long long* __restrict__ mbits) {
#pragma clang fp contract(off)
  int row = blockIdx.x * 256 + threadIdx.x;
  const float* q = qk + (size_t)row * ND;
  double r[8];
#pragma unroll
  for (int j = 0; j < 8; ++j) { double x = (double)q[j]; r[j] = x * x; }
#pragma unroll
  for (int i = 8; i < 64; i += 8)
#pragma unroll
    for (int j = 0; j < 8; ++j) { double x = (double)q[i + j]; r[j] += x * x; }
  double nrm = sqrt(pw8(r));
  atomicMax(mbits, (unsigned long long)__double_as_longlong(nrm));  // positive: bit order == value order
}

// ---- K2: per-row c, Q — bit-faithful numpy f64 (exact IEEE divides, pairwise sums).
__global__ __launch_bounds__(256) void krn_cq(const float* __restrict__ qk,
                                              const float* __restrict__ a,
                                              const unsigned long long* __restrict__ mbits,
                                              double* __restrict__ c64,
                                              double* __restrict__ q64) {
#pragma clang fp contract(off)
  int row = blockIdx.x * 256 + threadIdx.x;
  const float* q  = qk + (size_t)row * ND;
  const float* ar = a  + (size_t)row * NSD;
  double M = __longlong_as_double((long long)*mbits);
  double r[8], s[8];
#pragma unroll
  for (int j = 0; j < 8; ++j) {
    double u = (double)q[j] / M;          // correctly-rounded f64 divide (matches np)
    r[j] = u * u;
    s[j] = u * (double)ar[j];
  }
#pragma unroll
  for (int i = 8; i < 64; i += 8)
#pragma unroll
    for (int j = 0; j < 8; ++j) {
      double u = (double)q[i + j] / M;
      r[j] += u * u;
      s[j] += u * (double)ar[i + j];
    }
  double cn = sqrt(pw8(r));
  double t  = cn * cn;                    // separate rounding (contract off)
  double c  = sqrt(1.0 - t);              // NaN possible at argmax row — faithful & deterministic
  double res = pw8(s);
  res = res + c * (double)ar[64];         // pairwise n=66 tail: sequential adds of b[64], b[65]
  res = res + 0.0 * (double)ar[65];
  c64[row] = c;
  q64[row] = res;
}

// ---- helper: per-row exact top-k + f32 mask write (f64 sortable keys in ACC regs)
__device__ __forceinline__ void proc_row(double (&ACC)[32], int t, double a65,
                                         const double* __restrict__ cS,
                                         const double* __restrict__ qS,
                                         int k, int bh, int lane,
                                         unsigned long long ltmask,
                                         float* __restrict__ out) {
  // scores -> NaN-fix -> sortable u64 (in place)
#pragma unroll
  for (int j = 0; j < 32; ++j) {
    int s = lane + 64 * j;
    double inner = ACC[j] + cS[s] * a65;
    double sc = qS[s] * inner;
    if (sc != sc) sc = 0.0;
    long long b = __double_as_longlong(sc);
    ACC[j] = __longlong_as_double(b ^ ((b >> 63) | (long long)0x8000000000000000ULL));
  }
  // level 1: binary search on high 32 bits of sortable key
  unsigned long long lo = 0ull, hi = 1ull << 32;
#pragma unroll 1
  for (int it = 0; it < 32; ++it) {
    unsigned long long mid = lo + ((hi - lo) >> 1);
    int cnt = 0;
#pragma unroll
    for (int j = 0; j < 32; ++j) {
      unsigned long long su = (unsigned long long)__double_as_longlong(ACC[j]);
      cnt += ((su >> 32) >= mid) ? 1 : 0;
    }
#pragma unroll
    for (int off = 32; off >= 1; off >>= 1) cnt += __shfl_xor(cnt, off);
    if (cnt >= k) lo = mid; else hi = mid;
  }
  unsigned long long v32 = lo;
  int gt32 = 0, eq32 = 0;
#pragma unroll
  for (int j = 0; j < 32; ++j) {
    unsigned long long h = (unsigned long long)__double_as_longlong(ACC[j]) >> 32;
    gt32 += (h > v32) ? 1 : 0;
    eq32 += (h == v32) ? 1 : 0;
  }
#pragma unroll
  for (int off = 32; off >= 1; off >>= 1) { gt32 += __shfl_xor(gt32, off); eq32 += __shfl_xor(eq32, off); }
  int esel = k - gt32;
  float* orow = out + (size_t)(bh * NS + t) * NS;

  if (eq32 == esel) {   // exact fill at high-32 granularity (common case)
#pragma unroll
    for (int j = 0; j < 32; ++j) {
      unsigned long long h = (unsigned long long)__double_as_longlong(ACC[j]) >> 32;
      orow[lane + 64 * j] = (h >= v32) ? 0.0f : MVAL;
    }
  } else {              // level 2: resolve within the high-32 tie group on low 32 bits
    unsigned long long lo2 = 0ull, hi2 = 1ull << 32;
#pragma unroll 1
    for (int it = 0; it < 32; ++it) {
      unsigned long long mid = lo2 + ((hi2 - lo2) >> 1);
      int cnt = 0;
#pragma unroll
      for (int j = 0; j < 32; ++j) {
        unsigned long long su = (unsigned long long)__double_as_longlong(ACC[j]);
        cnt += (((su >> 32) == v32) && ((su & 0xFFFFFFFFull) >= mid)) ? 1 : 0;
      }
#pragma unroll
      for (int off = 32; off >= 1; off >>= 1) cnt += __shfl_xor(cnt, off);
      if (cnt >= esel) lo2 = mid; else hi2 = mid;
    }
    unsigned long long L = lo2;
    int gtL = 0;
#pragma unroll
    for (int j = 0; j < 32; ++j) {
      unsigned long long su = (unsigned long long)__double_as_longlong(ACC[j]);
      gtL += (((su >> 32) == v32) && ((su & 0xFFFFFFFFull) > L)) ? 1 : 0;
    }
#pragma unroll
    for (int off = 32; off >= 1; off >>= 1) gtL += __shfl_xor(gtL, off);
    int eselL = esel - gtL;   // ties at full 64 bits kept lowest-index-first
    int cum = 0;
#pragma unroll
    for (int j = 0; j < 32; ++j) {
      unsigned long long su = (unsigned long long)__double_as_longlong(ACC[j]);
      unsigned long long h = su >> 32, lw = su & 0xFFFFFFFFull;
      bool eq = (h == v32) && (lw == L);
      unsigned long long bj = __ballot(eq);
      int rank = cum + __popcll(bj & ltmask);
      cum += __popcll(bj);
      bool sel = (h > v32) || ((h == v32) && ((lw > L) || (eq && rank < eselL)));
      orow[lane + 64 * j] = sel ? 0.0f : MVAL;
    }
  }
}

// ---- K3: f64 score GEMM + exact top-k + f32 mask write.
// Grid: 16 bh x 256 tiles; block 256 (4 waves); wave owns 2 t-rows, all 2048 s.
__global__ __launch_bounds__(256, 1) void krn_mask(
    const float* __restrict__ qk, const float* __restrict__ a,
    const unsigned long long* __restrict__ mbits,
    const double* __restrict__ c64, const double* __restrict__ q64,
    const int* __restrict__ bsz, float* __restrict__ out) {
  __shared__ __align__(16) double uLDS[64 * 64];   // 32 KB, pair-XOR swizzled
  __shared__ __align__(16) double aLDS[8][66];     // 8 t-rows (f64)

  int bh   = blockIdx.x >> 8;
  int tile = blockIdx.x & 255;
  int tid  = threadIdx.x, wv = tid >> 6, lane = tid & 63;
  int t0   = tile * 8;
  const float* qkS = qk + (size_t)bh * NS * ND;
  const float* aS  = a  + (size_t)bh * NS * NSD;
  const double* cS = c64 + (size_t)bh * NS;
  const double* qS = q64 + (size_t)bh * NS;
  int k = *bsz;
  double M  = __longlong_as_double((long long)*mbits);
  double r1 = 1.0 / M;

  for (int i = tid; i < 8 * NSD; i += 256) {
    int rr = i / NSD, dd = i - rr * NSD;
    aLDS[rr][dd] = (double)aS[(size_t)(t0 + rr) * NSD + dd];
  }

  double acc0[32], acc1[32];
  int srow = tid >> 2;          // staging row within chunk
  int spb  = (tid & 3) * 8;     // pair base (8 pairs = 16 doubles)
  const double* arow0 = aLDS[wv * 2 + 0];
  const double* arow1 = aLDS[wv * 2 + 1];

#pragma unroll
  for (int cc = 0; cc < 32; ++cc) {    // FULL unroll: acc indices static (no scratch)
    __syncthreads();
    {  // stage 64 rows of u = qk/M in f64 (Markstein exact quotient)
      const float* src = qkS + (size_t)(cc * 64 + srow) * ND + spb * 2;
#pragma unroll
      for (int qq = 0; qq < 8; ++qq) {
        float2 v = *(const float2*)(src + qq * 2);
        double x0 = (double)v.x, x1 = (double)v.y;
        double q0 = x0 * r1; double e0 = fma(-M, q0, x0); double u0 = fma(e0, r1, q0);
        double q1 = x1 * r1; double e1 = fma(-M, q1, x1); double u1 = fma(e1, r1, q1);
        int P = spb + qq;
        int pos = P ^ (srow & 31);
        double2 w2; w2.x = u0; w2.y = u1;
        *(double2*)(&uLDS[srow * 64 + pos * 2]) = w2;
      }
    }
    __syncthreads();
    double d0 = 0.0, d1 = 0.0;
#pragma unroll
    for (int P = 0; P < 32; ++P) {
      int pos = P ^ (lane & 31);
      double2 u2 = *(const double2*)(&uLDS[lane * 64 + pos * 2]);
      double2 a0 = *(const double2*)(&arow0[2 * P]);
      double2 a1 = *(const double2*)(&arow1[2 * P]);
      d0 = fma(u2.x, a0.x, d0); d0 = fma(u2.y, a0.y, d0);
      d1 = fma(u2.x, a1.x, d1); d1 = fma(u2.y, a1.y, d1);
    }
    acc0[cc] = d0; acc1[cc] = d1;
  }

  unsigned long long ltmask = (1ull << lane) - 1ull;
  proc_row(acc0, t0 + wv * 2 + 0, aLDS[wv * 2 + 0][65], cS, qS, k, bh, lane, ltmask, out);
  proc_row(acc1, t0 + wv * 2 + 1, aLDS[wv * 2 + 1][65], cS, qS, k, bh, lane, ltmask, out);
}

extern "C" void kernel_launch(void* const* d_in, const int* in_sizes, int n_in,
                              void* d_out, int out_size, void* d_ws, size_t ws_size,
                              hipStream_t stream) {
  const float* qk = (const float*)d_in[0];
  const float* a  = (const float*)d_in[1];
  const int* bs   = (const int*)d_in[2];
  float* out = (float*)d_out;

  char* w = (char*)d_ws;
  unsigned long long* mbits = (unsigned long long*)w;          // 8 B
  double* c64 = (double*)(w + 4096);                           // 32768 f64
  double* q64 = (double*)(w + 4096 + (size_t)NROWS * 8);       // 32768 f64

  hipMemsetAsync(w, 0, 64, stream);
  krn_m   <<<NROWS / 256, 256, 0, stream>>>(qk, mbits);
  krn_cq  <<<NROWS / 256, 256, 0, stream>>>(qk, a, mbits, c64, q64);
  krn_mask<<<NBH * 256, 256, 0, stream>>>(qk, a, mbits, c64, q64, bs, out);
}

// Round 10
// 941.093 us; speedup vs baseline: 2.2973x; 2.2973x over previous
//
#include <hip/hip_runtime.h>

#define NBH   16
#define NS    2048
#define ND    64
#define NSD   66
#define NROWS 32768
#define MVAL  (-10000.0f)

// numpy pairwise-8 combine
__device__ __forceinline__ double pw8(const double* r) {
  return ((r[0] + r[1]) + (r[2] + r[3])) + ((r[4] + r[5]) + (r[6] + r[7]));
}
// Exact IEEE f32 quotient via Markstein
__device__ __forceinline__ float mdiv(float v, float M, float r1) {
  float q0 = v * r1;
  float e  = fmaf(-M, q0, v);
  return fmaf(e, r1, q0);
}

// ---- K1: per-row f64 norm (numpy pairwise); atomicMax of bits. [PASSED r9]
__global__ __launch_bounds__(256) void krn_m(const float* __restrict__ qk,
                                             unsigned long long* __restrict__ mbits) {
#pragma clang fp contract(off)
  int row = blockIdx.x * 256 + threadIdx.x;
  const float* q = qk + (size_t)row * ND;
  double r[8];
#pragma unroll
  for (int j = 0; j < 8; ++j) { double x = (double)q[j]; r[j] = x * x; }
#pragma unroll
  for (int i = 8; i < 64; i += 8)
#pragma unroll
    for (int j = 0; j < 8; ++j) { double x = (double)q[i + j]; r[j] += x * x; }
  double nrm = sqrt(pw8(r));
  atomicMax(mbits, (unsigned long long)__double_as_longlong(nrm));
}

// ---- K2: per-row c, Q in f64 (+f32 copies). [PASSED r9, outputs extended]
__global__ __launch_bounds__(256) void krn_cq(const float* __restrict__ qk,
                                              const float* __restrict__ a,
                                              const unsigned long long* __restrict__ mbits,
                                              double* __restrict__ c64, double* __restrict__ q64,
                                              float* __restrict__ c32, float* __restrict__ q32) {
#pragma clang fp contract(off)
  int row = blockIdx.x * 256 + threadIdx.x;
  const float* q  = qk + (size_t)row * ND;
  const float* ar = a  + (size_t)row * NSD;
  double M = __longlong_as_double((long long)*mbits);
  double r[8], s[8];
#pragma unroll
  for (int j = 0; j < 8; ++j) {
    double u = (double)q[j] / M;
    r[j] = u * u;
    s[j] = u * (double)ar[j];
  }
#pragma unroll
  for (int i = 8; i < 64; i += 8)
#pragma unroll
    for (int j = 0; j < 8; ++j) {
      double u = (double)q[i + j] / M;
      r[j] += u * u;
      s[j] += u * (double)ar[i + j];
    }
  double cn = sqrt(pw8(r));
  double t  = cn * cn;
  double c  = sqrt(1.0 - t);              // NaN possible at argmax row — faithful
  double res = pw8(s);
  res = res + c * (double)ar[64];
  res = res + 0.0 * (double)ar[65];
  c64[row] = c; q64[row] = res;
  c32[row] = (float)c; q32[row] = (float)res;
}

// ---- K3: u = qk/M (f32), transposed to [bh][d][s] for coalesced GEMM loads.
__global__ __launch_bounds__(256) void krn_ut(const float* __restrict__ qk,
                                              const unsigned long long* __restrict__ mbits,
                                              float* __restrict__ ut) {
  __shared__ float tl[64][65];
  int b = blockIdx.x, tid = threadIdx.x;
  float M = (float)__longlong_as_double((long long)*mbits);
  float r1 = 1.0f / M;
  int r0 = tid >> 2, c0 = (tid & 3) * 16;
  const float* src = qk + ((size_t)b * 64 + r0) * 64 + c0;
#pragma unroll
  for (int i = 0; i < 4; ++i) {
    float4 v = *(const float4*)(src + i * 4);
    tl[r0][c0 + i*4 + 0] = mdiv(v.x, M, r1);
    tl[r0][c0 + i*4 + 1] = mdiv(v.y, M, r1);
    tl[r0][c0 + i*4 + 2] = mdiv(v.z, M, r1);
    tl[r0][c0 + i*4 + 3] = mdiv(v.w, M, r1);
  }
  __syncthreads();
  int bh = b >> 5, s0 = (b & 31) * 64;
  int d = tid >> 2, sl = (tid & 3) * 16;
  float* dst = ut + ((size_t)bh * 64 + d) * NS + s0 + sl;
#pragma unroll
  for (int i = 0; i < 4; ++i) {
    float4 w;
    w.x = tl[sl + i*4 + 0][d];
    w.y = tl[sl + i*4 + 1][d];
    w.z = tl[sl + i*4 + 2][d];
    w.w = tl[sl + i*4 + 3][d];
    *(float4*)(dst + i * 4) = w;
  }
}

// ---- per-row f32 top-k + near-tie flag + mask write
__device__ __forceinline__ void sel_row(float (&A)[32], int t, float a65,
                                        const float* __restrict__ cS,
                                        const float* __restrict__ qS,
                                        int k, int bh, int lane,
                                        int* __restrict__ flags,
                                        float* __restrict__ out) {
#pragma unroll
  for (int j = 0; j < 32; ++j) {
    int s = lane + 64 * j;
    float sc = qS[s] * fmaf(cS[s], a65, A[j]);
    sc = (sc != sc) ? 0.0f : sc;
    int b = __float_as_int(sc);
    unsigned su = (unsigned)b ^ (unsigned)((b >> 31) | 0x80000000);
    A[j] = __uint_as_float(su);
  }
  unsigned lo = 0u, hi = 0xFFFFFFFFu;
#pragma unroll 1
  for (int it = 0; it < 32; ++it) {
    unsigned mid = lo + ((hi - lo) >> 1);
    int cnt = 0;
#pragma unroll
    for (int j = 0; j < 32; ++j) cnt += (__float_as_uint(A[j]) >= mid) ? 1 : 0;
#pragma unroll
    for (int off = 32; off >= 1; off >>= 1) cnt += __shfl_xor(cnt, off);
    if (cnt >= k) lo = mid; else hi = mid;
  }
  int nn = 0;
#pragma unroll
  for (int j = 0; j < 32; ++j) {
    long long d = (long long)__float_as_uint(A[j]) - (long long)lo;
    nn += ((d < 0 ? -d : d) <= 1024) ? 1 : 0;   // near-tie window: 1024 f32 ulps
  }
#pragma unroll
  for (int off = 32; off >= 1; off >>= 1) nn += __shfl_xor(nn, off);
  if (nn > 1 && lane == 0) flags[bh * NS + t] = 1;   // f64 refine will overwrite row
  float* orow = out + (size_t)(bh * NS + t) * NS;
#pragma unroll
  for (int j = 0; j < 32; ++j)
    orow[lane + 64 * j] = (__float_as_uint(A[j]) >= lo) ? 0.0f : MVAL;
}

// ---- K4: f32 score GEMM (no LDS staging, no hot-loop barriers) + top-k.
// Grid 16 bh x 128 tiles(16 t); 4 waves; wave owns 4 t-rows x all 2048 s.
__global__ __launch_bounds__(256, 2) void krn_mask(
    const float* __restrict__ ut, const float* __restrict__ a,
    const float* __restrict__ c32, const float* __restrict__ q32,
    const int* __restrict__ bsz, int* __restrict__ flags,
    float* __restrict__ out) {
  __shared__ float aLDS[16 * 68];
  int bh = blockIdx.x >> 7, tile = blockIdx.x & 127;
  int tid = threadIdx.x, wv = tid >> 6, lane = tid & 63;
  int t0 = tile * 16;
  const float* aS  = a + (size_t)bh * NS * NSD;
  const float* utS = ut + (size_t)bh * 64 * NS;
  const float* cS  = c32 + bh * NS;
  const float* qS  = q32 + bh * NS;
  int k = *bsz;
  for (int i = tid; i < 16 * NSD; i += 256) {
    int rr = i / NSD, dd = i - rr * NSD;
    aLDS[rr * 68 + dd] = aS[(size_t)(t0 + rr) * NSD + dd];
  }
  __syncthreads();

  float acc[4][32];
#pragma unroll
  for (int r = 0; r < 4; ++r)
#pragma unroll
    for (int j = 0; j < 32; ++j) acc[r][j] = 0.f;

  const float* ar0 = &aLDS[(wv * 4 + 0) * 68];
  const float* ar1 = &aLDS[(wv * 4 + 1) * 68];
  const float* ar2 = &aLDS[(wv * 4 + 2) * 68];
  const float* ar3 = &aLDS[(wv * 4 + 3) * 68];

#pragma unroll 1
  for (int d = 0; d < 64; ++d) {
    float a0 = ar0[d], a1 = ar1[d], a2 = ar2[d], a3 = ar3[d];
    const float* up = utS + (size_t)d * NS + lane;
    float uu[32];
#pragma unroll
    for (int j = 0; j < 32; ++j) uu[j] = up[j << 6];   // coalesced 4B/lane
#pragma unroll
    for (int j = 0; j < 32; ++j) {
      acc[0][j] = fmaf(uu[j], a0, acc[0][j]);
      acc[1][j] = fmaf(uu[j], a1, acc[1][j]);
      acc[2][j] = fmaf(uu[j], a2, acc[2][j]);
      acc[3][j] = fmaf(uu[j], a3, acc[3][j]);
    }
  }

  sel_row(acc[0], t0 + wv * 4 + 0, ar0[65], cS, qS, k, bh, lane, flags, out);
  sel_row(acc[1], t0 + wv * 4 + 1, ar1[65], cS, qS, k, bh, lane, flags, out);
  sel_row(acc[2], t0 + wv * 4 + 2, ar2[65], cS, qS, k, bh, lane, flags, out);
  sel_row(acc[3], t0 + wv * 4 + 3, ar3[65], cS, qS, k, bh, lane, flags, out);
}

// ---- K5: f64 refine of flagged rows — mirrors r9's PASSED arithmetic.
__global__ __launch_bounds__(256) void krn_refine(
    const float* __restrict__ qk, const float* __restrict__ a,
    const unsigned long long* __restrict__ mbits,
    const double* __restrict__ c64, const double* __restrict__ q64,
    const int* __restrict__ flags, const int* __restrict__ bsz,
    float* __restrict__ out) {
  __shared__ unsigned long long sU[NS];
  __shared__ double aRow[NSD];
  __shared__ int redI[4];
  __shared__ unsigned char selmap[NS];
  int tid = threadIdx.x, wv = tid >> 6, lane = tid & 63;
  double M = __longlong_as_double((long long)*mbits);
  int k = *bsz;
#pragma unroll 1
  for (int row = blockIdx.x; row < NROWS; row += 1024) {
    if (flags[row] == 0) continue;          // uniform per block
    int bh = row >> 11, t = row & (NS - 1);
    if (tid < NSD) aRow[tid] = (double)a[((size_t)bh * NS + t) * NSD + tid];
    __syncthreads();
    double a65 = aRow[65];
#pragma unroll 1
    for (int j = 0; j < 8; ++j) {
      int s = tid + 256 * j;
      const float* qr = qk + ((size_t)bh * NS + s) * ND;
      double accd = 0.0;
#pragma unroll
      for (int d = 0; d < ND; ++d) accd = fma((double)qr[d] / M, aRow[d], accd);
      double inner = accd + c64[bh * NS + s] * a65;   // same exprs as r9 proc_row
      double sc = q64[bh * NS + s] * inner;
      if (sc != sc) sc = 0.0;
      long long b = __double_as_longlong(sc);
      sU[s] = (unsigned long long)(b ^ ((b >> 63) | (long long)0x8000000000000000LL));
    }
    __syncthreads();
    unsigned long long lo = 0ull, hi = ~0ull;
#pragma unroll 1
    for (int it = 0; it < 64; ++it) {
      unsigned long long mid = lo + ((hi - lo) >> 1);
      int c = 0;
#pragma unroll
      for (int j = 0; j < 8; ++j) c += (sU[tid + 256 * j] >= mid) ? 1 : 0;
#pragma unroll
      for (int off = 32; off >= 1; off >>= 1) c += __shfl_xor(c, off);
      if (lane == 0) redI[wv] = c;
      __syncthreads();
      int tot = redI[0] + redI[1] + redI[2] + redI[3];
      if (tot >= k) lo = mid; else hi = mid;
      __syncthreads();
    }
    int pk = 0;
#pragma unroll
    for (int j = 0; j < 8; ++j) {
      unsigned long long su = sU[tid + 256 * j];
      pk += (su > lo) ? (1 << 12) : 0;
      pk += (su == lo) ? 1 : 0;
    }
#pragma unroll
    for (int off = 32; off >= 1; off >>= 1) pk += __shfl_xor(pk, off);
    if (lane == 0) redI[wv] = pk;
    __syncthreads();
    int tot = redI[0] + redI[1] + redI[2] + redI[3];
    int GT = tot >> 12, EQ = tot & 0xFFF;
    int esel = k - GT;
#pragma unroll
    for (int j = 0; j < 8; ++j) {
      int s = tid + 256 * j;
      selmap[s] = (sU[s] > lo) ? 1 : 0;
    }
    __syncthreads();
    if (EQ == esel) {
#pragma unroll
      for (int j = 0; j < 8; ++j) {
        int s = tid + 256 * j;
        if (sU[s] == lo) selmap[s] = 1;
      }
    } else if (tid == 0) {
      int r = 0;
      for (int s = 0; s < NS; ++s)
        if (sU[s] == lo) { selmap[s] = (r < esel) ? 1 : 0; ++r; }
    }
    __syncthreads();
    float* orow = out + (size_t)row * NS;
#pragma unroll
    for (int j = 0; j < 8; ++j) {
      int s = tid + 256 * j;
      orow[s] = selmap[s] ? 0.0f : MVAL;
    }
    __syncthreads();
  }
}

extern "C" void kernel_launch(void* const* d_in, const int* in_sizes, int n_in,
                              void* d_out, int out_size, void* d_ws, size_t ws_size,
                              hipStream_t stream) {
  const float* qk = (const float*)d_in[0];
  const float* a  = (const float*)d_in[1];
  const int* bs   = (const int*)d_in[2];
  float* out = (float*)d_out;

  char* w = (char*)d_ws;
  unsigned long long* mbits = (unsigned long long*)w;       // @0
  int*    flags = (int*)   (w + 4096);                      // 128 KB
  double* c64   = (double*)(w + 139264);                    // 256 KB
  double* q64   = (double*)(w + 401408);                    // 256 KB
  float*  c32   = (float*) (w + 663552);                    // 128 KB
  float*  q32   = (float*) (w + 794624);                    // 128 KB
  float*  ut    = (float*) (w + 925696);                    // 8 MB

  hipMemsetAsync(w, 0, 4096 + NROWS * 4, stream);
  krn_m     <<<NROWS / 256, 256, 0, stream>>>(qk, mbits);
  krn_cq    <<<NROWS / 256, 256, 0, stream>>>(qk, a, mbits, c64, q64, c32, q32);
  krn_ut    <<<NROWS / 64,  256, 0, stream>>>(qk, mbits, ut);
  krn_mask  <<<NBH * 128,   256, 0, stream>>>(ut, a, c32, q32, bs, flags, out);
  krn_refine<<<1024,        256, 0, stream>>>(qk, a, mbits, c64, q64, flags, bs, out);
}

// Round 11
// 738.355 us; speedup vs baseline: 2.9280x; 1.2746x over previous
//
#include <hip/hip_runtime.h>

#define NBH   16
#define NS    2048
#define ND    64
#define NSD   66
#define NROWS 32768
#define MVAL  (-10000.0f)

__device__ __forceinline__ double pw8(const double* r) {
  return ((r[0] + r[1]) + (r[2] + r[3])) + ((r[4] + r[5]) + (r[6] + r[7]));
}
// Exact IEEE f32 quotient via Markstein
__device__ __forceinline__ float mdiv(float v, float M, float r1) {
  float q0 = v * r1;
  float e  = fmaf(-M, q0, v);
  return fmaf(e, r1, q0);
}
// Exact IEEE f64 quotient via Markstein (r1 = RN(1/M)); bit-identical to x/M
__device__ __forceinline__ double mdiv64(double x, double M, double r1) {
  double q0 = x * r1;
  double e  = fma(-M, q0, x);
  return fma(e, r1, q0);
}

// ---- K1: per-row f64 norm (numpy pairwise); atomicMax of bits. [PASSED r9/r10]
__global__ __launch_bounds__(256) void krn_m(const float* __restrict__ qk,
                                             unsigned long long* __restrict__ mbits) {
#pragma clang fp contract(off)
  int row = blockIdx.x * 256 + threadIdx.x;
  const float* q = qk + (size_t)row * ND;
  double r[8];
#pragma unroll
  for (int j = 0; j < 8; ++j) { double x = (double)q[j]; r[j] = x * x; }
#pragma unroll
  for (int i = 8; i < 64; i += 8)
#pragma unroll
    for (int j = 0; j < 8; ++j) { double x = (double)q[i + j]; r[j] += x * x; }
  double nrm = sqrt(pw8(r));
  atomicMax(mbits, (unsigned long long)__double_as_longlong(nrm));
}

// ---- K2: per-row c, Q in f64 (+f32 copies). [PASSED r9/r10]
__global__ __launch_bounds__(256) void krn_cq(const float* __restrict__ qk,
                                              const float* __restrict__ a,
                                              const unsigned long long* __restrict__ mbits,
                                              double* __restrict__ c64, double* __restrict__ q64,
                                              float* __restrict__ c32, float* __restrict__ q32) {
#pragma clang fp contract(off)
  int row = blockIdx.x * 256 + threadIdx.x;
  const float* q  = qk + (size_t)row * ND;
  const float* ar = a  + (size_t)row * NSD;
  double M = __longlong_as_double((long long)*mbits);
  double r[8], s[8];
#pragma unroll
  for (int j = 0; j < 8; ++j) {
    double u = (double)q[j] / M;
    r[j] = u * u;
    s[j] = u * (double)ar[j];
  }
#pragma unroll
  for (int i = 8; i < 64; i += 8)
#pragma unroll
    for (int j = 0; j < 8; ++j) {
      double u = (double)q[i + j] / M;
      r[j] += u * u;
      s[j] += u * (double)ar[i + j];
    }
  double cn = sqrt(pw8(r));
  double t  = cn * cn;
  double c  = sqrt(1.0 - t);              // NaN possible at argmax row — faithful
  double res = pw8(s);
  res = res + c * (double)ar[64];
  res = res + 0.0 * (double)ar[65];
  c64[row] = c; q64[row] = res;
  c32[row] = (float)c; q32[row] = (float)res;
}

// ---- K3: u = qk/M (f32), transposed to [bh][d][s]. [PASSED r10]
__global__ __launch_bounds__(256) void krn_ut(const float* __restrict__ qk,
                                              const unsigned long long* __restrict__ mbits,
                                              float* __restrict__ ut) {
  __shared__ float tl[64][65];
  int b = blockIdx.x, tid = threadIdx.x;
  float M = (float)__longlong_as_double((long long)*mbits);
  float r1 = 1.0f / M;
  int r0 = tid >> 2, c0 = (tid & 3) * 16;
  const float* src = qk + ((size_t)b * 64 + r0) * 64 + c0;
#pragma unroll
  for (int i = 0; i < 4; ++i) {
    float4 v = *(const float4*)(src + i * 4);
    tl[r0][c0 + i*4 + 0] = mdiv(v.x, M, r1);
    tl[r0][c0 + i*4 + 1] = mdiv(v.y, M, r1);
    tl[r0][c0 + i*4 + 2] = mdiv(v.z, M, r1);
    tl[r0][c0 + i*4 + 3] = mdiv(v.w, M, r1);
  }
  __syncthreads();
  int bh = b >> 5, s0 = (b & 31) * 64;
  int d = tid >> 2, sl = (tid & 3) * 16;
  float* dst = ut + ((size_t)bh * 64 + d) * NS + s0 + sl;
#pragma unroll
  for (int i = 0; i < 4; ++i) {
    float4 w;
    w.x = tl[sl + i*4 + 0][d];
    w.y = tl[sl + i*4 + 1][d];
    w.z = tl[sl + i*4 + 2][d];
    w.w = tl[sl + i*4 + 3][d];
    *(float4*)(dst + i * 4) = w;
  }
}

// ---- per-row f32 top-k (s = j*256 + lane*4 + i mapping) + flag append + float4 mask write
__device__ __forceinline__ void sel_row(float (&A)[32], int t, float a65,
                                        const float* __restrict__ cS,
                                        const float* __restrict__ qS,
                                        int k, int bh, int lane,
                                        int* __restrict__ nflag, int* __restrict__ flaglist,
                                        float* __restrict__ out) {
#pragma unroll
  for (int j = 0; j < 8; ++j) {
    int sb = j * 256 + lane * 4;
    float4 c4 = *(const float4*)(cS + sb);
    float4 q4 = *(const float4*)(qS + sb);
#pragma unroll
    for (int i = 0; i < 4; ++i) {
      float cc = (i == 0) ? c4.x : (i == 1) ? c4.y : (i == 2) ? c4.z : c4.w;
      float qq = (i == 0) ? q4.x : (i == 1) ? q4.y : (i == 2) ? q4.z : q4.w;
      float sc = qq * fmaf(cc, a65, A[j * 4 + i]);
      sc = (sc != sc) ? 0.0f : sc;
      int b = __float_as_int(sc);
      unsigned su = (unsigned)b ^ (unsigned)((b >> 31) | 0x80000000);
      A[j * 4 + i] = __uint_as_float(su);
    }
  }
  unsigned lo = 0u, hi = 0xFFFFFFFFu;
#pragma unroll 1
  for (int it = 0; it < 32; ++it) {
    unsigned mid = lo + ((hi - lo) >> 1);
    int cnt = 0;
#pragma unroll
    for (int m = 0; m < 32; ++m) cnt += (__float_as_uint(A[m]) >= mid) ? 1 : 0;
#pragma unroll
    for (int off = 32; off >= 1; off >>= 1) cnt += __shfl_xor(cnt, off);
    if (cnt >= k) lo = mid; else hi = mid;
  }
  int nn = 0;
#pragma unroll
  for (int m = 0; m < 32; ++m) {
    long long d = (long long)__float_as_uint(A[m]) - (long long)lo;
    nn += ((d < 0 ? -d : d) <= 1024) ? 1 : 0;   // near-tie window: 1024 f32 ulps
  }
#pragma unroll
  for (int off = 32; off >= 1; off >>= 1) nn += __shfl_xor(nn, off);
  if (nn > 1 && lane == 0) {
    int ix = atomicAdd(nflag, 1);
    flaglist[ix] = bh * NS + t;                 // f64 refine will overwrite row
  }
  float* orow = out + (size_t)(bh * NS + t) * NS;
#pragma unroll
  for (int j = 0; j < 8; ++j) {
    float4 w;
    w.x = (__float_as_uint(A[j*4+0]) >= lo) ? 0.0f : MVAL;
    w.y = (__float_as_uint(A[j*4+1]) >= lo) ? 0.0f : MVAL;
    w.z = (__float_as_uint(A[j*4+2]) >= lo) ? 0.0f : MVAL;
    w.w = (__float_as_uint(A[j*4+3]) >= lo) ? 0.0f : MVAL;
    *(float4*)(orow + j * 256 + lane * 4) = w;
  }
}

// ---- K4: f32 score GEMM (float4 loads) + top-k. Grid 2048, XCD-bijective swizzle.
__global__ __launch_bounds__(256, 2) void krn_mask(
    const float* __restrict__ ut, const float* __restrict__ a,
    const float* __restrict__ c32, const float* __restrict__ q32,
    const int* __restrict__ bsz, int* __restrict__ nflag, int* __restrict__ flaglist,
    float* __restrict__ out) {
  __shared__ float aLDS[16 * 68];
  int wg = (blockIdx.x & 7) * 256 + (blockIdx.x >> 3);   // 8 XCDs x 256 contiguous
  int bh = wg >> 7, tile = wg & 127;
  int tid = threadIdx.x, wv = tid >> 6, lane = tid & 63;
  int t0 = tile * 16;
  const float* aS  = a + (size_t)bh * NS * NSD;
  const float* utS = ut + (size_t)bh * 64 * NS;
  const float* cS  = c32 + bh * NS;
  const float* qS  = q32 + bh * NS;
  int k = *bsz;
  for (int i = tid; i < 16 * NSD; i += 256) {
    int rr = i / NSD, dd = i - rr * NSD;
    aLDS[rr * 68 + dd] = aS[(size_t)(t0 + rr) * NSD + dd];
  }
  __syncthreads();

  float acc[4][32];
#pragma unroll
  for (int r = 0; r < 4; ++r)
#pragma unroll
    for (int m = 0; m < 32; ++m) acc[r][m] = 0.f;

  const float* ar0 = &aLDS[(wv * 4 + 0) * 68];
  const float* ar1 = &aLDS[(wv * 4 + 1) * 68];
  const float* ar2 = &aLDS[(wv * 4 + 2) * 68];
  const float* ar3 = &aLDS[(wv * 4 + 3) * 68];

#pragma unroll 1
  for (int d = 0; d < 64; ++d) {
    float a0 = ar0[d], a1 = ar1[d], a2 = ar2[d], a3 = ar3[d];
    const float* up = utS + (size_t)d * NS + (lane << 2);
#pragma unroll
    for (int j = 0; j < 8; ++j) {
      float4 u4 = *(const float4*)(up + j * 256);
      acc[0][j*4+0] = fmaf(u4.x, a0, acc[0][j*4+0]);
      acc[0][j*4+1] = fmaf(u4.y, a0, acc[0][j*4+1]);
      acc[0][j*4+2] = fmaf(u4.z, a0, acc[0][j*4+2]);
      acc[0][j*4+3] = fmaf(u4.w, a0, acc[0][j*4+3]);
      acc[1][j*4+0] = fmaf(u4.x, a1, acc[1][j*4+0]);
      acc[1][j*4+1] = fmaf(u4.y, a1, acc[1][j*4+1]);
      acc[1][j*4+2] = fmaf(u4.z, a1, acc[1][j*4+2]);
      acc[1][j*4+3] = fmaf(u4.w, a1, acc[1][j*4+3]);
      acc[2][j*4+0] = fmaf(u4.x, a2, acc[2][j*4+0]);
      acc[2][j*4+1] = fmaf(u4.y, a2, acc[2][j*4+1]);
      acc[2][j*4+2] = fmaf(u4.z, a2, acc[2][j*4+2]);
      acc[2][j*4+3] = fmaf(u4.w, a2, acc[2][j*4+3]);
      acc[3][j*4+0] = fmaf(u4.x, a3, acc[3][j*4+0]);
      acc[3][j*4+1] = fmaf(u4.y, a3, acc[3][j*4+1]);
      acc[3][j*4+2] = fmaf(u4.z, a3, acc[3][j*4+2]);
      acc[3][j*4+3] = fmaf(u4.w, a3, acc[3][j*4+3]);
    }
  }

  sel_row(acc[0], t0 + wv * 4 + 0, ar0[65], cS, qS, k, bh, lane, nflag, flaglist, out);
  sel_row(acc[1], t0 + wv * 4 + 1, ar1[65], cS, qS, k, bh, lane, nflag, flaglist, out);
  sel_row(acc[2], t0 + wv * 4 + 2, ar2[65], cS, qS, k, bh, lane, nflag, flaglist, out);
  sel_row(acc[3], t0 + wv * 4 + 3, ar3[65], cS, qS, k, bh, lane, nflag, flaglist, out);
}

// ---- K5: f64 refine of flagged rows (compacted list; 1 wave/block; r9 arithmetic).
__global__ __launch_bounds__(64) void krn_refine(
    const float* __restrict__ qk, const float* __restrict__ a,
    const unsigned long long* __restrict__ mbits,
    const double* __restrict__ c64, const double* __restrict__ q64,
    const int* __restrict__ nflag, const int* __restrict__ flaglist,
    const int* __restrict__ bsz, float* __restrict__ out) {
  __shared__ double aRow[NSD];
  int lane = threadIdx.x;
  double M = __longlong_as_double((long long)*mbits);
  double r1 = 1.0 / M;
  int k = *bsz;
  int n = *nflag;
  unsigned long long ltmask = (1ull << lane) - 1ull;
#pragma unroll 1
  for (int ii = blockIdx.x; ii < n; ii += 2048) {
    int row = flaglist[ii];
    int bh = row >> 11, t = row & (NS - 1);
    __syncthreads();
    for (int i = lane; i < NSD; i += 64)
      aRow[i] = (double)a[((size_t)bh * NS + t) * NSD + i];
    __syncthreads();
    double a65 = aRow[65];
    const double* cS = c64 + (size_t)bh * NS;
    const double* qS = q64 + (size_t)bh * NS;
    double ACC[32];
#pragma unroll 1
    for (int j = 0; j < 32; ++j) {
      int s = lane + 64 * j;
      const float* qr = qk + ((size_t)bh * NS + s) * ND;
      double accd = 0.0;
#pragma unroll
      for (int d = 0; d < ND; ++d)
        accd = fma(mdiv64((double)qr[d], M, r1), aRow[d], accd);
      double sc = qS[s] * (accd + cS[s] * a65);
      if (sc != sc) sc = 0.0;
      long long b = __double_as_longlong(sc);
      ACC[j] = __longlong_as_double(b ^ ((b >> 63) | (long long)0x8000000000000000ULL));
    }
    // level 1: binary search on high 32 bits (r9 proc_row verbatim)
    unsigned long long lo = 0ull, hi = 1ull << 32;
#pragma unroll 1
    for (int it = 0; it < 32; ++it) {
      unsigned long long mid = lo + ((hi - lo) >> 1);
      int cnt = 0;
#pragma unroll
      for (int j = 0; j < 32; ++j) {
        unsigned long long su = (unsigned long long)__double_as_longlong(ACC[j]);
        cnt += ((su >> 32) >= mid) ? 1 : 0;
      }
#pragma unroll
      for (int off = 32; off >= 1; off >>= 1) cnt += __shfl_xor(cnt, off);
      if (cnt >= k) lo = mid; else hi = mid;
    }
    unsigned long long v32 = lo;
    int gt32 = 0, eq32 = 0;
#pragma unroll
    for (int j = 0; j < 32; ++j) {
      unsigned long long h = (unsigned long long)__double_as_longlong(ACC[j]) >> 32;
      gt32 += (h > v32) ? 1 : 0;
      eq32 += (h == v32) ? 1 : 0;
    }
#pragma unroll
    for (int off = 32; off >= 1; off >>= 1) { gt32 += __shfl_xor(gt32, off); eq32 += __shfl_xor(eq32, off); }
    int esel = k - gt32;
    float* orow = out + (size_t)row * NS;
    if (eq32 == esel) {
#pragma unroll
      for (int j = 0; j < 32; ++j) {
        unsigned long long h = (unsigned long long)__double_as_longlong(ACC[j]) >> 32;
        orow[lane + 64 * j] = (h >= v32) ? 0.0f : MVAL;
      }
    } else {
      unsigned long long lo2 = 0ull, hi2 = 1ull << 32;
#pragma unroll 1
      for (int it = 0; it < 32; ++it) {
        unsigned long long mid = lo2 + ((hi2 - lo2) >> 1);
        int cnt = 0;
#pragma unroll
        for (int j = 0; j < 32; ++j) {
          unsigned long long su = (unsigned long long)__double_as_longlong(ACC[j]);
          cnt += (((su >> 32) == v32) && ((su & 0xFFFFFFFFull) >= mid)) ? 1 : 0;
        }
#pragma unroll
        for (int off = 32; off >= 1; off >>= 1) cnt += __shfl_xor(cnt, off);
        if (cnt >= esel) lo2 = mid; else hi2 = mid;
      }
      unsigned long long L = lo2;
      int gtL = 0;
#pragma unroll
      for (int j = 0; j < 32; ++j) {
        unsigned long long su = (unsigned long long)__double_as_longlong(ACC[j]);
        gtL += (((su >> 32) == v32) && ((su & 0xFFFFFFFFull) > L)) ? 1 : 0;
      }
#pragma unroll
      for (int off = 32; off >= 1; off >>= 1) gtL += __shfl_xor(gtL, off);
      int eselL = esel - gtL;
      int cum = 0;
#pragma unroll
      for (int j = 0; j < 32; ++j) {
        unsigned long long su = (unsigned long long)__double_as_longlong(ACC[j]);
        unsigned long long h = su >> 32, lw = su & 0xFFFFFFFFull;
        bool eq = (h == v32) && (lw == L);
        unsigned long long bj = __ballot(eq);
        int rank = cum + __popcll(bj & ltmask);
        cum += __popcll(bj);
        bool sel = (h > v32) || ((h == v32) && ((lw > L) || (eq && rank < eselL)));
        orow[lane + 64 * j] = sel ? 0.0f : MVAL;
      }
    }
  }
}

extern "C" void kernel_launch(void* const* d_in, const int* in_sizes, int n_in,
                              void* d_out, int out_size, void* d_ws, size_t ws_size,
                              hipStream_t stream) {
  const float* qk = (const float*)d_in[0];
  const float* a  = (const float*)d_in[1];
  const int* bs   = (const int*)d_in[2];
  float* out = (float*)d_out;

  char* w = (char*)d_ws;
  unsigned long long* mbits = (unsigned long long*)w;       // @0
  int*    nflag    = (int*)   (w + 64);
  int*    flaglist = (int*)   (w + 4096);                   // 128 KB
  double* c64      = (double*)(w + 139264);                 // 256 KB
  double* q64      = (double*)(w + 401408);                 // 256 KB
  float*  c32      = (float*) (w + 663552);                 // 128 KB
  float*  q32      = (float*) (w + 794624);                 // 128 KB
  float*  ut       = (float*) (w + 925696);                 // 8 MB

  hipMemsetAsync(w, 0, 4096, stream);
  krn_m     <<<NROWS / 256, 256, 0, stream>>>(qk, mbits);
  krn_cq    <<<NROWS / 256, 256, 0, stream>>>(qk, a, mbits, c64, q64, c32, q32);
  krn_ut    <<<NROWS / 64,  256, 0, stream>>>(qk, mbits, ut);
  krn_mask  <<<NBH * 128,   256, 0, stream>>>(ut, a, c32, q32, bs, nflag, flaglist, out);
  krn_refine<<<2048,        64,  0, stream>>>(qk, a, mbits, c64, q64, nflag, flaglist, bs, out);
}